// Round 7
// baseline (3301.362 us; speedup 1.0000x reference)
//
#include <hip/hip_runtime.h>
#include <hip/hip_bf16.h>
#include <hip/hip_fp16.h>

// sinogram: [1,16,360,736] f32, grid: [1,360,16384,2] f32,
// square_inv: [1,1,360,16384] f32, out: [1,16,16384] f32
#define NP 16384
#define NV 360
#define ND 736
#define NC 16
#define NREC (NV * NP)            // 5,898,240 points
#define QSZ (NV * ND * 8)         // ushorts per 8-channel half table
#define TBL_BYTES (2 * QSZ * 2)   // 8,478,720 B
#define NYB 45                    // y-bins of 8 rows
#define NPR 32                    // p-ranges of 512
#define NBUCKET (NYB * NPR)       // 1440
#define REC_OFF (TBL_BYTES + 3 * NBUCKET * 4)   // 8,496,000 (8B aligned)
#define WS_NEED (REC_OFF + (size_t)NREC * 8)    // ~55.7 MB
#define K4_LDS (9 * 736 * 16 + 512 * 9 * 4)     // 124,416 B

__device__ __forceinline__ float bf_lo(uint u) { return __uint_as_float(u << 16); }
__device__ __forceinline__ float bf_hi(uint u) { return __uint_as_float(u & 0xffff0000u); }

// K0: transpose+quantize sino -> two bf16 half-tables [Q][y][x][8ch];
// fused zeroing of d_out and bucket counters.
__global__ __launch_bounds__(256) void k0_transpose(const float* __restrict__ sino,
                                                    ushort* __restrict__ st,
                                                    float* __restrict__ out,
                                                    uint* cnt) {
    int idx = blockIdx.x * 256 + threadIdx.x;   // idx = y*ND + x
    if (cnt && idx < NBUCKET) cnt[idx] = 0;
    if (idx < NC * NP) out[idx] = 0.0f;
    if (idx >= NV * ND) return;
    uint packed[8];
#pragma unroll
    for (int q = 0; q < 8; ++q) {
        uint ul = __float_as_uint(sino[(2 * q)     * (NV * ND) + idx]);
        uint uh = __float_as_uint(sino[(2 * q + 1) * (NV * ND) + idx]);
        ul = (ul + 0x7fffu + ((ul >> 16) & 1u)) >> 16;   // RNE bf16
        uh = (uh + 0x7fffu + ((uh >> 16) & 1u)) >> 16;
        packed[q] = ul | (uh << 16);
    }
    uint4* d0 = reinterpret_cast<uint4*>(st + ((size_t)idx << 3));
    uint4* d1 = reinterpret_cast<uint4*>(st + QSZ + ((size_t)idx << 3));
    *d0 = make_uint4(packed[0], packed[1], packed[2], packed[3]);
    *d1 = make_uint4(packed[4], packed[5], packed[6], packed[7]);
}

// K1: per-bucket counts via LDS histogram. 1440 blocks x 4096 points.
__global__ __launch_bounds__(256) void k1_count(const float* __restrict__ grd,
                                                uint* __restrict__ cnt) {
    __shared__ uint h[NBUCKET];
    for (int i = threadIdx.x; i < NBUCKET; i += 256) h[i] = 0;
    __syncthreads();
    int base = blockIdx.x * 4096;
    const float2* grd2 = reinterpret_cast<const float2*>(grd);
#pragma unroll 4
    for (int k = 0; k < 16; ++k) {
        int gi = base + k * 256 + threadIdx.x;
        float gy = grd2[gi].y;
        float iy = ((gy + 1.0f) * (float)NV - 1.0f) * 0.5f;
        int y0 = min(max((int)floorf(iy), 0), NV - 1);
        int p = gi & (NP - 1);
        atomicAdd(&h[(y0 >> 3) * NPR + (p >> 9)], 1u);
    }
    __syncthreads();
    for (int i = threadIdx.x; i < NBUCKET; i += 256)
        if (h[i]) atomicAdd(&cnt[i], h[i]);
}

// K2: exclusive prefix over 1440 counts -> start[], cursor[]. One block.
__global__ __launch_bounds__(256) void k2_prefix(const uint* __restrict__ cnt,
                                                 uint* __restrict__ start,
                                                 uint* __restrict__ cursor) {
    __shared__ uint partial[256];
    int b0 = threadIdx.x * 6;
    uint s = 0;
    for (int j = 0; j < 6; ++j) { int b = b0 + j; if (b < NBUCKET) s += cnt[b]; }
    partial[threadIdx.x] = s;
    __syncthreads();
    for (int off = 1; off < 256; off <<= 1) {
        uint v = (threadIdx.x >= (uint)off) ? partial[threadIdx.x - off] : 0u;
        __syncthreads();
        partial[threadIdx.x] += v;
        __syncthreads();
    }
    uint base = (threadIdx.x > 0) ? partial[threadIdx.x - 1] : 0u;
    for (int j = 0; j < 6; ++j) {
        int b = b0 + j;
        if (b < NBUCKET) { start[b] = base; cursor[b] = base; base += cnt[b]; }
    }
}

// K3: compute 8B records, scatter into bucket regions via cursor atomics.
// meta: p_local:9 | yrel:3 | yf:1 | x0:10 | xf:1 | wxq:8
__global__ __launch_bounds__(256) void k3_scatter(const float* __restrict__ grd,
                                                  const float* __restrict__ sq,
                                                  uint* __restrict__ cursor,
                                                  uint2* __restrict__ rec) {
    int gi = blockIdx.x * 256 + threadIdx.x;
    float2 g = reinterpret_cast<const float2*>(grd)[gi];
    float w = sq[gi] * 1000.0f;

    float ix = ((g.x + 1.0f) * (float)ND - 1.0f) * 0.5f;
    float iy = ((g.y + 1.0f) * (float)NV - 1.0f) * 0.5f;
    float x0f = floorf(ix), y0f = floorf(iy);
    float wx = ix - x0f, wy = iy - y0f;       // weights from UNclamped floor
    int x0i = (int)x0f, y0i = (int)y0f;
    int x0 = min(max(x0i, 0), ND - 1);
    int y0 = min(max(y0i, 0), NV - 1);
    uint xf = (x0i >= 0 && x0i <= ND - 2) ? 1u : 0u;
    uint yf = (y0i >= 0 && y0i <= NV - 2) ? 1u : 0u;
    float a = w * (1.0f - wy), b = w * wy;    // row weights
    uint wxq = min((uint)(wx * 256.0f), 255u);

    int p = gi & (NP - 1);
    int bucket = (y0 >> 3) * NPR + (p >> 9);
    uint m = (uint)(p & 511) | ((uint)(y0 & 7) << 9) | (yf << 12)
           | ((uint)x0 << 13) | (xf << 23) | (wxq << 24);
    uint abp = (uint)__half_as_ushort(__float2half(a))
             | ((uint)__half_as_ushort(__float2half(b)) << 16);
    uint pos = atomicAdd(&cursor[bucket], 1u);
    rec[pos] = make_uint2(m, abp);
}

// K4: per (bucket, Q-half): stage 9 table rows + 512x8 tile (pad 9) in LDS;
// gather 4 corners per record from LDS, ds_add_f32 into tile; flush coalesced.
__global__ __launch_bounds__(1024) void k4_backproj(const ushort* __restrict__ tbl,
                                                    const uint* __restrict__ cnt,
                                                    const uint* __restrict__ start,
                                                    const uint2* __restrict__ rec,
                                                    float* __restrict__ out) {
    int bucket0 = blockIdx.x >> 1;
    int Q = blockIdx.x & 1;
    int ybr = bucket0 / NPR;
    int prange = bucket0 - ybr * NPR;
    // remap so heavy border y-bins (0,44) are dispatched first
    int ybin = (ybr & 1) ? (NYB - 1 - (ybr >> 1)) : (ybr >> 1);
    int bucket = ybin * NPR + prange;
    uint n = cnt[bucket];
    if (n == 0) return;

    extern __shared__ char smem[];
    uint4* rows = reinterpret_cast<uint4*>(smem);              // [9*736]
    float* tile = reinterpret_cast<float*>(smem + 9 * 736 * 16); // [512*9]

    const uint4* gtbl = reinterpret_cast<const uint4*>(tbl + (size_t)Q * QSZ);
    for (int j = threadIdx.x; j < 9 * 736; j += 1024) {
        int r = j / 736;
        int gr = min(ybin * 8 + r, NV - 1);
        rows[j] = gtbl[gr * 736 + (j - r * 736)];
    }
    for (int j = threadIdx.x; j < 512 * 9; j += 1024) tile[j] = 0.0f;
    __syncthreads();

    uint s0 = start[bucket];
    for (uint i = threadIdx.x; i < n; i += 1024) {
        uint2 rr = rec[s0 + i];
        uint m = rr.x;
        int pl = m & 511;
        int yr = (m >> 9) & 7;
        int yf = (m >> 12) & 1;
        int x0 = (m >> 13) & 1023;
        int xf = (m >> 23) & 1;
        float wx = (float)(m >> 24) * (1.0f / 256.0f) + (0.5f / 256.0f);
        float a = __half2float(__ushort_as_half((ushort)(rr.y & 0xffffu)));
        float b = __half2float(__ushort_as_half((ushort)(rr.y >> 16)));
        float w01 = a * wx, w00 = a - w01, w11 = b * wx, w10 = b - w11;
        int i00 = yr * 736 + x0;
        int i10 = i00 + yf * 736;
        uint4 v00 = rows[i00], v01 = rows[i00 + xf];
        uint4 v10 = rows[i10], v11 = rows[i10 + xf];
        float* t = &tile[pl * 9];
        atomicAdd(t + 0, bf_lo(v00.x)*w00 + bf_lo(v01.x)*w01 + bf_lo(v10.x)*w10 + bf_lo(v11.x)*w11);
        atomicAdd(t + 1, bf_hi(v00.x)*w00 + bf_hi(v01.x)*w01 + bf_hi(v10.x)*w10 + bf_hi(v11.x)*w11);
        atomicAdd(t + 2, bf_lo(v00.y)*w00 + bf_lo(v01.y)*w01 + bf_lo(v10.y)*w10 + bf_lo(v11.y)*w11);
        atomicAdd(t + 3, bf_hi(v00.y)*w00 + bf_hi(v01.y)*w01 + bf_hi(v10.y)*w10 + bf_hi(v11.y)*w11);
        atomicAdd(t + 4, bf_lo(v00.z)*w00 + bf_lo(v01.z)*w01 + bf_lo(v10.z)*w10 + bf_lo(v11.z)*w11);
        atomicAdd(t + 5, bf_hi(v00.z)*w00 + bf_hi(v01.z)*w01 + bf_hi(v10.z)*w10 + bf_hi(v11.z)*w11);
        atomicAdd(t + 6, bf_lo(v00.w)*w00 + bf_lo(v01.w)*w01 + bf_lo(v10.w)*w10 + bf_lo(v11.w)*w11);
        atomicAdd(t + 7, bf_hi(v00.w)*w00 + bf_hi(v01.w)*w01 + bf_hi(v10.w)*w10 + bf_hi(v11.w)*w11);
    }
    __syncthreads();

    int pbase = prange * 512;
    for (int j = threadIdx.x; j < 4096; j += 1024) {
        int c = j >> 9, pl = j & 511;
        float v = tile[pl * 9 + c];
        if (v != 0.0f) atomicAdd(&out[(Q * 8 + c) * NP + pbase + pl], v);
    }
}

// ---- Fallback (R6 proven path) if ws is too small for records ----
__global__ __launch_bounds__(256) void backproj_r6(const float* __restrict__ grd,
                                                   const float* __restrict__ sq,
                                                   const ushort* __restrict__ st,
                                                   float* __restrict__ out) {
    int Q    = blockIdx.x & 1;
    int r    = blockIdx.x >> 1;
    int pblk = r & 127;
    int vs   = r >> 7;
    int pr   = threadIdx.x >> 1;
    int c    = threadIdx.x & 1;
    int p    = pblk * 128 + pr;
    int v0 = (vs * NV) / 16, v1 = ((vs + 1) * NV) / 16;
    const ushort* tblp = st + Q * QSZ;
    float acc[8];
#pragma unroll
    for (int k = 0; k < 8; ++k) acc[k] = 0.0f;
    const float2* grd2 = reinterpret_cast<const float2*>(grd);
    for (int v = v0; v < v1; ++v) {
        int gi = v * NP + p;
        float2 g = grd2[gi];
        float w = sq[gi] * 1000.0f;
        float ix = ((g.x + 1.0f) * (float)ND - 1.0f) * 0.5f;
        float iy = ((g.y + 1.0f) * (float)NV - 1.0f) * 0.5f;
        float x0f = floorf(ix), y0f = floorf(iy);
        float wx = ix - x0f, wy = iy - y0f;
        int x0i = (int)x0f, y0i = (int)y0f;
        int x0 = min(max(x0i, 0), ND - 1);
        int x1 = min(max(x0i + 1, 0), ND - 1);
        int y0 = min(max(y0i, 0), NV - 1);
        int y1 = min(max(y0i + 1, 0), NV - 1);
        int xc = c ? x1 : x0;
        float wxc = (c ? wx : (1.0f - wx)) * w;
        uint4 a0 = *reinterpret_cast<const uint4*>(tblp + ((size_t)(y0 * ND + xc) << 3));
        uint4 a1 = *reinterpret_cast<const uint4*>(tblp + ((size_t)(y1 * ND + xc) << 3));
        float wa = wxc * (1.0f - wy), wb = wxc * wy;
        uint u0[4] = {a0.x, a0.y, a0.z, a0.w};
        uint u1[4] = {a1.x, a1.y, a1.z, a1.w};
#pragma unroll
        for (int q = 0; q < 4; ++q) {
            acc[2*q]   = fmaf(bf_lo(u0[q]), wa, fmaf(bf_lo(u1[q]), wb, acc[2*q]));
            acc[2*q+1] = fmaf(bf_hi(u0[q]), wa, fmaf(bf_hi(u1[q]), wb, acc[2*q+1]));
        }
    }
#pragma unroll
    for (int k = 0; k < 8; ++k) acc[k] += __shfl_xor(acc[k], 1);
    if (c == 0)
#pragma unroll
        for (int k = 0; k < 8; ++k)
            atomicAdd(&out[(Q * 8 + k) * NP + p], acc[k]);
}

extern "C" void kernel_launch(void* const* d_in, const int* in_sizes, int n_in,
                              void* d_out, int out_size, void* d_ws, size_t ws_size,
                              hipStream_t stream) {
    const float* sino = (const float*)d_in[0];
    const float* grd  = (const float*)d_in[1];
    const float* sq   = (const float*)d_in[2];
    float* out = (float*)d_out;
    char* base = (char*)d_ws;
    ushort* st = (ushort*)base;

    if (ws_size >= WS_NEED) {
        uint* cnt    = (uint*)(base + TBL_BYTES);
        uint* start  = cnt + NBUCKET;
        uint* cursor = start + NBUCKET;
        uint2* rec   = (uint2*)(base + REC_OFF);

        k0_transpose<<<(NV * ND + 255) / 256, 256, 0, stream>>>(sino, st, out, cnt);
        k1_count<<<NBUCKET, 256, 0, stream>>>(grd, cnt);
        k2_prefix<<<1, 256, 0, stream>>>(cnt, start, cursor);
        k3_scatter<<<NREC / 256, 256, 0, stream>>>(grd, sq, cursor, rec);

        static int attr_done = 0;
        (void)attr_done;  // hipFuncSetAttribute is idempotent + capture-safe
        hipFuncSetAttribute(reinterpret_cast<const void*>(k4_backproj),
                            hipFuncAttributeMaxDynamicSharedMemorySize, K4_LDS);
        k4_backproj<<<NBUCKET * 2, 1024, K4_LDS, stream>>>(st, cnt, start, rec, out);
    } else {
        k0_transpose<<<(NV * ND + 255) / 256, 256, 0, stream>>>(sino, st, out, nullptr);
        backproj_r6<<<2 * 128 * 16, 256, 0, stream>>>(grd, sq, st, out);
    }
}

// Round 9
// 754.598 us; speedup vs baseline: 4.3750x; 4.3750x over previous
//
#include <hip/hip_runtime.h>
#include <hip/hip_bf16.h>
#include <hip/hip_fp16.h>

// sinogram: [1,16,360,736] f32, grid: [1,360,16384,2] f32,
// square_inv: [1,1,360,16384] f32, out: [1,16,16384] f32
#define NP 16384
#define NV 360
#define ND 736
#define NC 16
#define NREC (NV * NP)            // 5,898,240 points
#define QSZ (NV * ND * 8)         // ushorts per 8-channel half table
#define TBL_BYTES (2 * QSZ * 2)   // 8,478,720 B
#define NYB 45                    // y-bins of 8 rows
#define NPR 32                    // p-ranges of 512
#define NBUCKET (NYB * NPR)       // 1440
#define REC_OFF (TBL_BYTES + 3 * NBUCKET * 4)   // 8,496,000 (8B aligned)
#define WS_NEED (REC_OFF + (size_t)NREC * 8)    // ~55.7 MB
#define K4_LDS (9 * 736 * 16 + 512 * 9 * 4)     // 124,416 B
#define K3BLK 2048
#define K3PTS 8

__device__ __forceinline__ float bf_lo(uint u) { return __uint_as_float(u << 16); }
__device__ __forceinline__ float bf_hi(uint u) { return __uint_as_float(u & 0xffff0000u); }

// K0: transpose+quantize sino -> two bf16 half-tables [Q][y][x][8ch];
// fused zeroing of d_out and bucket counters.
__global__ __launch_bounds__(256) void k0_transpose(const float* __restrict__ sino,
                                                    ushort* __restrict__ st,
                                                    float* __restrict__ out,
                                                    uint* cnt) {
    int idx = blockIdx.x * 256 + threadIdx.x;   // idx = y*ND + x
    if (cnt && idx < NBUCKET) cnt[idx] = 0;
    if (idx < NC * NP) out[idx] = 0.0f;
    if (idx >= NV * ND) return;
    uint packed[8];
#pragma unroll
    for (int q = 0; q < 8; ++q) {
        uint ul = __float_as_uint(sino[(2 * q)     * (NV * ND) + idx]);
        uint uh = __float_as_uint(sino[(2 * q + 1) * (NV * ND) + idx]);
        ul = (ul + 0x7fffu + ((ul >> 16) & 1u)) >> 16;   // RNE bf16
        uh = (uh + 0x7fffu + ((uh >> 16) & 1u)) >> 16;
        packed[q] = ul | (uh << 16);
    }
    uint4* d0 = reinterpret_cast<uint4*>(st + ((size_t)idx << 3));
    uint4* d1 = reinterpret_cast<uint4*>(st + QSZ + ((size_t)idx << 3));
    *d0 = make_uint4(packed[0], packed[1], packed[2], packed[3]);
    *d1 = make_uint4(packed[4], packed[5], packed[6], packed[7]);
}

// K1: per-bucket counts via LDS histogram. 1440 blocks x 4096 points.
__global__ __launch_bounds__(256) void k1_count(const float* __restrict__ grd,
                                                uint* __restrict__ cnt) {
    __shared__ uint h[NBUCKET];
    for (int i = threadIdx.x; i < NBUCKET; i += 256) h[i] = 0;
    __syncthreads();
    int base = blockIdx.x * 4096;
    const float2* grd2 = reinterpret_cast<const float2*>(grd);
#pragma unroll 4
    for (int k = 0; k < 16; ++k) {
        int gi = base + k * 256 + threadIdx.x;
        float gy = grd2[gi].y;
        float iy = ((gy + 1.0f) * (float)NV - 1.0f) * 0.5f;
        int y0 = min(max((int)floorf(iy), 0), NV - 1);
        int p = gi & (NP - 1);
        atomicAdd(&h[(y0 >> 3) * NPR + (p >> 9)], 1u);
    }
    __syncthreads();
    for (int i = threadIdx.x; i < NBUCKET; i += 256)
        if (h[i]) atomicAdd(&cnt[i], h[i]);
}

// K2: exclusive prefix over 1440 counts -> start[], cursor[]. One block.
__global__ __launch_bounds__(256) void k2_prefix(const uint* __restrict__ cnt,
                                                 uint* __restrict__ start,
                                                 uint* __restrict__ cursor) {
    __shared__ uint partial[256];
    int b0 = threadIdx.x * 6;
    uint s = 0;
    for (int j = 0; j < 6; ++j) { int b = b0 + j; if (b < NBUCKET) s += cnt[b]; }
    partial[threadIdx.x] = s;
    __syncthreads();
    for (int off = 1; off < 256; off <<= 1) {
        uint v = (threadIdx.x >= (uint)off) ? partial[threadIdx.x - off] : 0u;
        __syncthreads();
        partial[threadIdx.x] += v;
        __syncthreads();
    }
    uint base = (threadIdx.x > 0) ? partial[threadIdx.x - 1] : 0u;
    for (int j = 0; j < 6; ++j) {
        int b = b0 + j;
        if (b < NBUCKET) { start[b] = base; cursor[b] = base; base += cnt[b]; }
    }
}

// K3 v2: block-aggregated scatter. Each block ranks its 2048 points in an LDS
// histogram (fast LDS atomics), reserves per-bucket space with ONE global
// atomic per touched bucket (~130/block vs 2048), then writes records at
// base+rank (contiguous chunks per bucket -> far less write-allocate waste).
// meta m: p_local:9 | yrel:3 | yf:1 | x0:10 | xf:1 | wxq:8
__global__ __launch_bounds__(256) void k3_scatter(const float* __restrict__ grd,
                                                  const float* __restrict__ sq,
                                                  uint* __restrict__ cursor,
                                                  uint2* __restrict__ rec) {
    __shared__ uint lcnt[NBUCKET];
    __shared__ uint lbase[NBUCKET];
    for (int i = threadIdx.x; i < NBUCKET; i += 256) lcnt[i] = 0;
    __syncthreads();

    int base = blockIdx.x * K3BLK;
    const float2* grd2 = reinterpret_cast<const float2*>(grd);
    uint2 r[K3PTS];
    uint  br[K3PTS];   // bucket<<16 | rank
#pragma unroll
    for (int k = 0; k < K3PTS; ++k) {
        int gi = base + k * 256 + threadIdx.x;
        float2 g = grd2[gi];
        float w = sq[gi] * 1000.0f;

        float ix = ((g.x + 1.0f) * (float)ND - 1.0f) * 0.5f;
        float iy = ((g.y + 1.0f) * (float)NV - 1.0f) * 0.5f;
        float x0f = floorf(ix), y0f = floorf(iy);
        float wx = ix - x0f, wy = iy - y0f;   // weights from UNclamped floor
        int x0i = (int)x0f, y0i = (int)y0f;
        int x0 = min(max(x0i, 0), ND - 1);
        int y0 = min(max(y0i, 0), NV - 1);
        uint xf = (x0i >= 0 && x0i <= ND - 2) ? 1u : 0u;
        uint yf = (y0i >= 0 && y0i <= NV - 2) ? 1u : 0u;
        float a = w * (1.0f - wy), b = w * wy;
        uint wxq = min((uint)(wx * 256.0f), 255u);

        int p = gi & (NP - 1);
        uint bucket = (uint)((y0 >> 3) * NPR + (p >> 9));
        uint m = (uint)(p & 511) | ((uint)(y0 & 7) << 9) | (yf << 12)
               | ((uint)x0 << 13) | (xf << 23) | (wxq << 24);
        uint abp = (uint)__half_as_ushort(__float2half(a))
                 | ((uint)__half_as_ushort(__float2half(b)) << 16);
        r[k] = make_uint2(m, abp);
        uint rk = atomicAdd(&lcnt[bucket], 1u);
        br[k] = (bucket << 16) | rk;
    }
    __syncthreads();

    for (int i = threadIdx.x; i < NBUCKET; i += 256)
        if (lcnt[i]) lbase[i] = atomicAdd(&cursor[i], lcnt[i]);
    __syncthreads();

#pragma unroll
    for (int k = 0; k < K3PTS; ++k)
        rec[lbase[br[k] >> 16] + (br[k] & 0xffffu)] = r[k];
}

// K4: per (bucket, Q-half): stage 9 table rows + 512x8 tile (pad 9) in LDS;
// gather 4 corners per record from LDS, ds_add_f32 into tile; flush coalesced.
__global__ __launch_bounds__(1024) void k4_backproj(const ushort* __restrict__ tbl,
                                                    const uint* __restrict__ cnt,
                                                    const uint* __restrict__ start,
                                                    const uint2* __restrict__ rec,
                                                    float* __restrict__ out) {
    int bucket0 = blockIdx.x >> 1;
    int Q = blockIdx.x & 1;
    int ybr = bucket0 / NPR;
    int prange = bucket0 - ybr * NPR;
    // remap so heavy border y-bins (0,44) are dispatched first
    int ybin = (ybr & 1) ? (NYB - 1 - (ybr >> 1)) : (ybr >> 1);
    int bucket = ybin * NPR + prange;
    uint n = cnt[bucket];
    if (n == 0) return;

    extern __shared__ char smem[];
    uint4* rows = reinterpret_cast<uint4*>(smem);                // [9*736]
    float* tile = reinterpret_cast<float*>(smem + 9 * 736 * 16); // [512*9]

    const uint4* gtbl = reinterpret_cast<const uint4*>(tbl + (size_t)Q * QSZ);
    for (int j = threadIdx.x; j < 9 * 736; j += 1024) {
        int r = j / 736;
        int gr = min(ybin * 8 + r, NV - 1);
        rows[j] = gtbl[gr * 736 + (j - r * 736)];
    }
    for (int j = threadIdx.x; j < 512 * 9; j += 1024) tile[j] = 0.0f;
    __syncthreads();

    uint s0 = start[bucket];
    for (uint i = threadIdx.x; i < n; i += 1024) {
        uint2 rr = rec[s0 + i];
        uint m = rr.x;
        int pl = m & 511;
        int yr = (m >> 9) & 7;
        int yf = (m >> 12) & 1;
        int x0 = (m >> 13) & 1023;
        int xf = (m >> 23) & 1;
        float wx = (float)(m >> 24) * (1.0f / 256.0f) + (0.5f / 256.0f);
        float a = __half2float(__ushort_as_half((ushort)(rr.y & 0xffffu)));
        float b = __half2float(__ushort_as_half((ushort)(rr.y >> 16)));
        float w01 = a * wx, w00 = a - w01, w11 = b * wx, w10 = b - w11;
        int i00 = yr * 736 + x0;
        int i10 = i00 + yf * 736;
        uint4 v00 = rows[i00], v01 = rows[i00 + xf];
        uint4 v10 = rows[i10], v11 = rows[i10 + xf];
        float* t = &tile[pl * 9];
        atomicAdd(t + 0, bf_lo(v00.x)*w00 + bf_lo(v01.x)*w01 + bf_lo(v10.x)*w10 + bf_lo(v11.x)*w11);
        atomicAdd(t + 1, bf_hi(v00.x)*w00 + bf_hi(v01.x)*w01 + bf_hi(v10.x)*w10 + bf_hi(v11.x)*w11);
        atomicAdd(t + 2, bf_lo(v00.y)*w00 + bf_lo(v01.y)*w01 + bf_lo(v10.y)*w10 + bf_lo(v11.y)*w11);
        atomicAdd(t + 3, bf_hi(v00.y)*w00 + bf_hi(v01.y)*w01 + bf_hi(v10.y)*w10 + bf_hi(v11.y)*w11);
        atomicAdd(t + 4, bf_lo(v00.z)*w00 + bf_lo(v01.z)*w01 + bf_lo(v10.z)*w10 + bf_lo(v11.z)*w11);
        atomicAdd(t + 5, bf_hi(v00.z)*w00 + bf_hi(v01.z)*w01 + bf_hi(v10.z)*w10 + bf_hi(v11.z)*w11);
        atomicAdd(t + 6, bf_lo(v00.w)*w00 + bf_lo(v01.w)*w01 + bf_lo(v10.w)*w10 + bf_lo(v11.w)*w11);
        atomicAdd(t + 7, bf_hi(v00.w)*w00 + bf_hi(v01.w)*w01 + bf_hi(v10.w)*w10 + bf_hi(v11.w)*w11);
    }
    __syncthreads();

    int pbase = prange * 512;
    for (int j = threadIdx.x; j < 4096; j += 1024) {
        int c = j >> 9, pl = j & 511;
        float v = tile[pl * 9 + c];
        if (v != 0.0f) atomicAdd(&out[(Q * 8 + c) * NP + pbase + pl], v);
    }
}

// ---- Fallback (R6 proven path) if ws is too small for records ----
__global__ __launch_bounds__(256) void backproj_r6(const float* __restrict__ grd,
                                                   const float* __restrict__ sq,
                                                   const ushort* __restrict__ st,
                                                   float* __restrict__ out) {
    int Q    = blockIdx.x & 1;
    int r    = blockIdx.x >> 1;
    int pblk = r & 127;
    int vs   = r >> 7;
    int pr   = threadIdx.x >> 1;
    int c    = threadIdx.x & 1;
    int p    = pblk * 128 + pr;
    int v0 = (vs * NV) / 16, v1 = ((vs + 1) * NV) / 16;
    const ushort* tblp = st + Q * QSZ;
    float acc[8];
#pragma unroll
    for (int k = 0; k < 8; ++k) acc[k] = 0.0f;
    const float2* grd2 = reinterpret_cast<const float2*>(grd);
    for (int v = v0; v < v1; ++v) {
        int gi = v * NP + p;
        float2 g = grd2[gi];
        float w = sq[gi] * 1000.0f;
        float ix = ((g.x + 1.0f) * (float)ND - 1.0f) * 0.5f;
        float iy = ((g.y + 1.0f) * (float)NV - 1.0f) * 0.5f;
        float x0f = floorf(ix), y0f = floorf(iy);
        float wx = ix - x0f, wy = iy - y0f;
        int x0i = (int)x0f, y0i = (int)y0f;
        int x0 = min(max(x0i, 0), ND - 1);
        int x1 = min(max(x0i + 1, 0), ND - 1);
        int y0 = min(max(y0i, 0), NV - 1);
        int y1 = min(max(y0i + 1, 0), NV - 1);
        int xc = c ? x1 : x0;
        float wxc = (c ? wx : (1.0f - wx)) * w;
        uint4 a0 = *reinterpret_cast<const uint4*>(tblp + ((size_t)(y0 * ND + xc) << 3));
        uint4 a1 = *reinterpret_cast<const uint4*>(tblp + ((size_t)(y1 * ND + xc) << 3));
        float wa = wxc * (1.0f - wy), wb = wxc * wy;
        uint u0[4] = {a0.x, a0.y, a0.z, a0.w};
        uint u1[4] = {a1.x, a1.y, a1.z, a1.w};
#pragma unroll
        for (int q = 0; q < 4; ++q) {
            acc[2*q]   = fmaf(bf_lo(u0[q]), wa, fmaf(bf_lo(u1[q]), wb, acc[2*q]));
            acc[2*q+1] = fmaf(bf_hi(u0[q]), wa, fmaf(bf_hi(u1[q]), wb, acc[2*q+1]));
        }
    }
#pragma unroll
    for (int k = 0; k < 8; ++k) acc[k] += __shfl_xor(acc[k], 1);
    if (c == 0)
#pragma unroll
        for (int k = 0; k < 8; ++k)
            atomicAdd(&out[(Q * 8 + k) * NP + p], acc[k]);
}

extern "C" void kernel_launch(void* const* d_in, const int* in_sizes, int n_in,
                              void* d_out, int out_size, void* d_ws, size_t ws_size,
                              hipStream_t stream) {
    const float* sino = (const float*)d_in[0];
    const float* grd  = (const float*)d_in[1];
    const float* sq   = (const float*)d_in[2];
    float* out = (float*)d_out;
    char* base = (char*)d_ws;
    ushort* st = (ushort*)base;

    if (ws_size >= WS_NEED) {
        uint* cnt    = (uint*)(base + TBL_BYTES);
        uint* start  = cnt + NBUCKET;
        uint* cursor = start + NBUCKET;
        uint2* rec   = (uint2*)(base + REC_OFF);

        k0_transpose<<<(NV * ND + 255) / 256, 256, 0, stream>>>(sino, st, out, cnt);
        k1_count<<<NBUCKET, 256, 0, stream>>>(grd, cnt);
        k2_prefix<<<1, 256, 0, stream>>>(cnt, start, cursor);
        k3_scatter<<<NREC / K3BLK, 256, 0, stream>>>(grd, sq, cursor, rec);

        hipFuncSetAttribute(reinterpret_cast<const void*>(k4_backproj),
                            hipFuncAttributeMaxDynamicSharedMemorySize, K4_LDS);
        k4_backproj<<<NBUCKET * 2, 1024, K4_LDS, stream>>>(st, cnt, start, rec, out);
    } else {
        k0_transpose<<<(NV * ND + 255) / 256, 256, 0, stream>>>(sino, st, out, nullptr);
        backproj_r6<<<2 * 128 * 16, 256, 0, stream>>>(grd, sq, st, out);
    }
}

// Round 11
// 225.155 us; speedup vs baseline: 14.6626x; 3.3515x over previous
//
#include <hip/hip_runtime.h>
#include <hip/hip_bf16.h>

// sinogram: [1,16,360,736] f32, grid: [1,360,16384,2] f32,
// square_inv: [1,1,360,16384] f32, out: [1,16,16384] f32
#define NP 16384
#define NV 360
#define ND 736
#define NC 16
#define VS 8                 // view chunks of 45

__device__ __forceinline__ float bf_lo(uint u) { return __uint_as_float(u << 16); }
__device__ __forceinline__ float bf_hi(uint u) { return __uint_as_float(u & 0xffff0000u); }

// K0: transpose+quantize sino [C][H*W] f32 -> [H*W][16ch] bf16 (32B per corner,
// so one point's corner-pair (x0,x1) spans at most two 64B lines). Fused d_out zeroing.
__global__ __launch_bounds__(256) void k0_transpose(const float* __restrict__ sino,
                                                    ushort* __restrict__ st,
                                                    float* __restrict__ out) {
    int idx = blockIdx.x * 256 + threadIdx.x;   // idx = y*ND + x
    if (idx < NC * NP) out[idx] = 0.0f;         // 262144 <= 264960 threads
    if (idx >= NV * ND) return;
    uint packed[8];
#pragma unroll
    for (int q = 0; q < 8; ++q) {
        uint ul = __float_as_uint(sino[(2 * q)     * (NV * ND) + idx]);
        uint uh = __float_as_uint(sino[(2 * q + 1) * (NV * ND) + idx]);
        // round-to-nearest-even bf16
        ul = (ul + 0x7fffu + ((ul >> 16) & 1u)) >> 16;
        uh = (uh + 0x7fffu + ((uh >> 16) & 1u)) >> 16;
        packed[q] = ul | (uh << 16);
    }
    uint4* dst = reinterpret_cast<uint4*>(st + ((size_t)idx << 4));
    dst[0] = make_uint4(packed[0], packed[1], packed[2], packed[3]);
    dst[1] = make_uint4(packed[4], packed[5], packed[6], packed[7]);
}

// Backproj: lane QUADS (4i..4i+3) own one pixel. sub = {x-side, channel-half}:
//   lane 4i+0: (x0, ch0-7)   lane 4i+1: (x1, ch0-7)
//   lane 4i+2: (x0, ch8-15)  lane 4i+3: (x1, ch8-15)
// Per view, each lane does 2 gathers (row y0, row y1). The quad's 4 addresses
// per row live in the 32B corners at [y][x0..x1] -> <=2 distinct 64B lines
// (avg 1.5), vs 2.5 in the Q-split layout: tests line-merge as the gather cost.
__global__ __launch_bounds__(256) void backproj(const float* __restrict__ grd,
                                                const float* __restrict__ sq,
                                                const ushort* __restrict__ st,
                                                float* __restrict__ out) {
    int tid  = threadIdx.x;
    int p    = ((blockIdx.x & 255) << 6) + (tid >> 2);   // 64 pixels per block
    int vs   = blockIdx.x >> 8;
    int sub  = tid & 3;
    int side = sub & 1;          // 0: x0, 1: x1
    int half = sub >> 1;         // 0: ch0-7, 1: ch8-15
    int v0 = vs * (NV / VS);     // 45-view chunks
    int v1 = v0 + (NV / VS);

    float acc[8];
#pragma unroll
    for (int k = 0; k < 8; ++k) acc[k] = 0.0f;

    const float2* grd2 = reinterpret_cast<const float2*>(grd);
    const uint4*  tbl  = reinterpret_cast<const uint4*>(st);

#pragma unroll 2
    for (int v = v0; v < v1; ++v) {
        int gi = v * NP + p;
        float2 g = grd2[gi];                 // quad lanes share addr (merges)
        float w  = sq[gi] * 1000.0f;

        // unnormalize, align_corners=False (exact reference formula)
        float ix = ((g.x + 1.0f) * (float)ND - 1.0f) * 0.5f;
        float iy = ((g.y + 1.0f) * (float)NV - 1.0f) * 0.5f;
        float x0f = floorf(ix), y0f = floorf(iy);
        float wx = ix - x0f,   wy = iy - y0f;    // weights from UNclamped floor
        int x0i = (int)x0f, y0i = (int)y0f;
        int x0 = min(max(x0i,     0), ND - 1);
        int x1 = min(max(x0i + 1, 0), ND - 1);
        int y0 = min(max(y0i,     0), NV - 1);
        int y1 = min(max(y0i + 1, 0), NV - 1);

        int   xc  = side ? x1 : x0;              // my x-side
        float wxc = (side ? wx : (1.0f - wx)) * w;

        uint4 a = tbl[((y0 * ND + xc) << 1) + half];   // row y0, my 16B half
        uint4 b = tbl[((y1 * ND + xc) << 1) + half];   // row y1, my 16B half
        float wa = wxc * (1.0f - wy);
        float wb = wxc * wy;

        uint ua[4] = {a.x, a.y, a.z, a.w};
        uint ub[4] = {b.x, b.y, b.z, b.w};
#pragma unroll
        for (int q = 0; q < 4; ++q) {
            acc[2*q]   = fmaf(bf_lo(ua[q]), wa, fmaf(bf_lo(ub[q]), wb, acc[2*q]));
            acc[2*q+1] = fmaf(bf_hi(ua[q]), wa, fmaf(bf_hi(ub[q]), wb, acc[2*q+1]));
        }
    }

    // combine x-sides within the quad, then even lanes write their half's channels
#pragma unroll
    for (int k = 0; k < 8; ++k) acc[k] += __shfl_xor(acc[k], 1);
    if (side == 0) {
#pragma unroll
        for (int k = 0; k < 8; ++k)
            atomicAdd(&out[(half * 8 + k) * NP + p], acc[k]);
    }
}

extern "C" void kernel_launch(void* const* d_in, const int* in_sizes, int n_in,
                              void* d_out, int out_size, void* d_ws, size_t ws_size,
                              hipStream_t stream) {
    const float* sino = (const float*)d_in[0];
    const float* grd  = (const float*)d_in[1];
    const float* sq   = (const float*)d_in[2];
    float* out = (float*)d_out;
    ushort* st = (ushort*)d_ws;           // 360*736*16*2B = 8.5 MB

    {
        int n = NV * ND;                  // also covers NC*NP out-zeroing
        k0_transpose<<<(n + 255) / 256, 256, 0, stream>>>(sino, st, out);
    }
    {
        int nblocks = 256 * VS;           // (NP/64) x VS = 2048 blocks
        backproj<<<nblocks, 256, 0, stream>>>(grd, sq, st, out);
    }
}